// Round 5
// baseline (220.878 us; speedup 1.0000x reference)
//
#include <hip/hip_runtime.h>
#include <hip/hip_fp16.h>

typedef unsigned short u16;
using f32x4 = __attribute__((ext_vector_type(4))) float;
using half8 = __attribute__((ext_vector_type(8))) _Float16;
using us8   = __attribute__((ext_vector_type(8))) unsigned short;

#define N_PTS 8192
#define D_DIM 768
#define TOPK  21
#define KSTEPS 12
#define CAPL  12
#define CAPG  320

// ---------------- async global->LDS (16B per lane) ----------------
__device__ __forceinline__ void gload16(const void* g, void* l) {
    __builtin_amdgcn_global_load_lds(
        (const __attribute__((address_space(1))) void*)g,
        (__attribute__((address_space(3))) void*)l,
        16, 0, 0);
}

// ---------------- wave (64-lane) reductions ----------------
__device__ __forceinline__ int wred_sum_i(int c) {
#pragma unroll
    for (int o = 32; o >= 1; o >>= 1) c += __shfl_xor(c, o, 64);
    return c;
}
__device__ __forceinline__ float wred_sum_f(float c) {
#pragma unroll
    for (int o = 32; o >= 1; o >>= 1) c += __shfl_xor(c, o, 64);
    return c;
}
__device__ __forceinline__ float wred_min_f(float c) {
#pragma unroll
    for (int o = 32; o >= 1; o >>= 1) c = fminf(c, __shfl_xor(c, o, 64));
    return c;
}

// ---------------- kernel 1: fp32 -> fp16 + row norms + zero counters ----
__global__ __launch_bounds__(256) void prep_kernel(const float* __restrict__ X,
                                                   u16* __restrict__ Xh,
                                                   float* __restrict__ norms,
                                                   int* __restrict__ cnt_g) {
    const int row = blockIdx.x;
    const int tid = threadIdx.x;
    const float* xr = X + (size_t)row * D_DIM;
    u16* hr = Xh + (size_t)row * D_DIM;
    float s = 0.f;
#pragma unroll
    for (int i = 0; i < 3; ++i) {
        float v = xr[tid + i * 256];
        _Float16 h = (_Float16)v;
        u16 hb;
        __builtin_memcpy(&hb, &h, 2);
        hr[tid + i * 256] = hb;
        float vb = (float)h;
        s += vb * vb;
    }
#pragma unroll
    for (int o = 32; o >= 1; o >>= 1) s += __shfl_down(s, o, 64);
    __shared__ float red[4];
    if ((tid & 63) == 0) red[tid >> 6] = s;
    __syncthreads();
    if (tid == 0) {
        norms[row] = red[0] + red[1] + red[2] + red[3];
        cnt_g[row] = 0;
    }
}

// ---------------- unified 256x256 GEMM: MODE 0 = tau (store d2 fp16),
//                  MODE 1 = full-matrix threshold filter ----
// 512 threads = 8 waves (2M x 4N); per-wave output 128x64; BK=64.
// Counted-vmcnt double-buffer: stage(t+2) after the barrier ending tile t's
// reads; only wait is vmcnt(8) (tile t done, tile t+1 in flight).
template<int MODE>
__global__ __launch_bounds__(512, 1) void gemm_main(const u16* __restrict__ Xh,
                                                    const float* __restrict__ norms,
                                                    const float* __restrict__ tauB,
                                                    u16* __restrict__ d2h,
                                                    float* __restrict__ cand_g,
                                                    int* __restrict__ cnt_g) {
    __shared__ __align__(16) u16 As[2][256 * 64];   // 64 KiB
    __shared__ __align__(16) u16 Bs[2][256 * 64];   // 64 KiB
    __shared__ float nAs[256];
    __shared__ float nBs[256];
    __shared__ float thrA[256];

    const int tid  = threadIdx.x;
    const int lane = tid & 63;
    const int wid  = tid >> 6;
    const int wr   = wid >> 2;       // 0..1 -> M half (128 rows)
    const int wc   = wid & 3;        // 0..3 -> N quarter (64 cols)
    const int l16  = lane >> 4;
    const int l15  = lane & 15;

    int rowTile, colTile;
    if (MODE == 0) {                 // 32x4 tiles over 8192x1024
        const int swz = (blockIdx.x & 7) * 16 + (blockIdx.x >> 3);
        rowTile = swz >> 2; colTile = swz & 3;
    } else {                         // 32x32 tiles over 8192x8192
        const int swz = (blockIdx.x & 7) * 128 + (blockIdx.x >> 3);
        rowTile = swz >> 5; colTile = swz & 31;
    }
    const int r0 = rowTile * 256;
    const int c0 = colTile * 256;

    if (tid < 256) {
        const float na = norms[r0 + tid];
        nAs[tid] = na;
        nBs[tid] = norms[c0 + tid];
        if (MODE == 1) thrA[tid] = 0.5f * (na - tauB[r0 + tid]);
    }

    f32x4 acc[8][4];
#pragma unroll
    for (int m = 0; m < 8; ++m)
#pragma unroll
        for (int n = 0; n < 4; ++n) {
            f32x4 z = {0.f, 0.f, 0.f, 0.f};
            acc[m][n] = z;
        }

    // stage K-tile t into slot s; 8 gload16/thread (uniform across waves -> exact vmcnt)
    // source chunk pre-swizzled (ch ^ row&7), LDS dest linear (rule #21)
    auto STAGE = [&](int t, int s) {
        const int kofs = t * 64;
#pragma unroll
        for (int j = 0; j < 4; ++j) {
            const int idx = j * 512 + tid;
            const int row = idx >> 3;
            const int ch  = (idx & 7) ^ (row & 7);
            gload16(Xh + (size_t)(r0 + row) * D_DIM + kofs + ch * 8, &As[s][idx * 8]);
        }
#pragma unroll
        for (int j = 0; j < 4; ++j) {
            const int idx = j * 512 + tid;
            const int row = idx >> 3;
            const int ch  = (idx & 7) ^ (row & 7);
            gload16(Xh + (size_t)(c0 + row) * D_DIM + kofs + ch * 8, &Bs[s][idx * 8]);
        }
    };

    __syncthreads();                 // drain pre-loop vm ops -> clean per-wave vmcnt
    STAGE(0, 0);
    __builtin_amdgcn_sched_barrier(0);
    STAGE(1, 1);
    __builtin_amdgcn_sched_barrier(0);

    for (int t = 0; t < KSTEPS; ++t) {
        const int sl = t & 1;
        // wait: tile t's 8 loads done; tile t+1's 8 may remain in flight
        if (t == KSTEPS - 1) { asm volatile("s_waitcnt vmcnt(0)"); }
        else                 { asm volatile("s_waitcnt vmcnt(8)"); }
        __builtin_amdgcn_sched_barrier(0);
        __builtin_amdgcn_s_barrier();        // tile t visible to all waves
        __builtin_amdgcn_sched_barrier(0);

#pragma unroll
        for (int kk = 0; kk < 2; ++kk) {
            half8 bf[4];
#pragma unroll
            for (int n = 0; n < 4; ++n) {
                const int rb = wc * 64 + n * 16 + l15;
                const int ch = (kk * 4 + l16) ^ (rb & 7);
                bf[n] = *reinterpret_cast<const half8*>(&Bs[sl][rb * 64 + ch * 8]);
            }
#pragma unroll
            for (int mh = 0; mh < 2; ++mh) {
                half8 af[4];
#pragma unroll
                for (int m = 0; m < 4; ++m) {
                    const int ra = wr * 128 + (mh * 4 + m) * 16 + l15;
                    const int ch = (kk * 4 + l16) ^ (ra & 7);
                    af[m] = *reinterpret_cast<const half8*>(&As[sl][ra * 64 + ch * 8]);
                }
                __builtin_amdgcn_s_setprio(1);
#pragma unroll
                for (int m = 0; m < 4; ++m)
#pragma unroll
                    for (int n = 0; n < 4; ++n)
                        acc[mh * 4 + m][n] = __builtin_amdgcn_mfma_f32_16x16x32_f16(
                            af[m], bf[n], acc[mh * 4 + m][n], 0, 0, 0);
                __builtin_amdgcn_s_setprio(0);
            }
        }

        if (t + 2 < KSTEPS) {
            asm volatile("s_waitcnt lgkmcnt(0)");   // my slot-sl reads complete
            __builtin_amdgcn_sched_barrier(0);
            __builtin_amdgcn_s_barrier();           // ALL waves done reading slot sl
            __builtin_amdgcn_sched_barrier(0);
            STAGE(t + 2, sl);                       // safe: slot sl free
            __builtin_amdgcn_sched_barrier(0);
        }
    }

    if (MODE == 0) {
        // ---- tau epilogue: store d2 as fp16 to d2h[8192][1024] ----
        float nAr[8], nBc[4];
#pragma unroll
        for (int m = 0; m < 8; ++m) nAr[m] = 0.f;   // placeholder, real read below
#pragma unroll
        for (int n = 0; n < 4; ++n) nBc[n] = nBs[wc * 64 + n * 16 + l15];
#pragma unroll
        for (int m = 0; m < 8; ++m)
#pragma unroll
            for (int r = 0; r < 4; ++r) {
                const int ra = wr * 128 + m * 16 + l16 * 4 + r;
                const float na = nAs[ra];
#pragma unroll
                for (int n = 0; n < 4; ++n) {
                    const int ci = c0 + wc * 64 + n * 16 + l15;
                    float d2 = fmaxf(na + nBc[n] - 2.0f * acc[m][n][r], 0.0f);
                    _Float16 h = (_Float16)d2;
                    u16 hb;
                    __builtin_memcpy(&hb, &h, 2);
                    d2h[(size_t)(r0 + ra) * 1024 + ci] = hb;
                }
            }
        (void)nAr;
    } else {
        // ---- filter epilogue; reuse slot-0 LDS for candidate lists ----
        float* candL = (float*)&As[0][0];     // [256][CAPL]
        int*   cntL  = (int*)&Bs[0][0];       // [256]
        if (tid < 256) cntL[tid] = 0;
        __syncthreads();

        float nBc[4], hb[4];
#pragma unroll
        for (int n = 0; n < 4; ++n) {
            const int ci = wc * 64 + n * 16 + l15;
            nBc[n] = nBs[ci];
            hb[n]  = 0.5f * nBc[n];
        }

#pragma unroll
        for (int m = 0; m < 8; ++m)
#pragma unroll
            for (int r = 0; r < 4; ++r) {
                const int ri  = wr * 128 + m * 16 + l16 * 4 + r;
                const float thr = thrA[ri];
                const float na  = nAs[ri];
#pragma unroll
                for (int n = 0; n < 4; ++n) {
                    const float d = acc[m][n][r];
                    if (d > thr + hb[n]) {
                        const float val = na + nBc[n] - 2.0f * d;
                        const int idx = atomicAdd(&cntL[ri], 1);
                        if (idx < CAPL) {
                            candL[ri * CAPL + idx] = val;
                        } else {               // rare overflow: spill to global
                            const int g = atomicAdd(&cnt_g[r0 + ri], 1);
                            if (g < CAPG) cand_g[(size_t)(r0 + ri) * CAPG + g] = val;
                        }
                    }
                }
            }

        __syncthreads();
        if (tid < 256) {
            const int row = r0 + tid;
            const int c = (cntL[tid] < CAPL) ? cntL[tid] : CAPL;
            if (c > 0) {
                const int base = atomicAdd(&cnt_g[row], c);
                for (int j = 0; j < c; ++j) {
                    const int s = base + j;
                    if (s < CAPG) cand_g[(size_t)row * CAPG + s] = candL[tid * CAPL + j];
                }
            }
        }
    }
}

// ---------------- kernel 3: per-row 21st-smallest of sample (bit search) ----
__global__ __launch_bounds__(256) void tau_select_kernel(const u16* __restrict__ d2h,
                                                         float* __restrict__ tauB) {
    const int tid  = threadIdx.x;
    const int lane = tid & 63;
    const int row  = blockIdx.x * 4 + (tid >> 6);

    const us8* p = (const us8*)(d2h + (size_t)row * 1024);
    us8 v0 = p[lane * 2];
    us8 v1 = p[lane * 2 + 1];

    unsigned lo = 0, hi = 0x7BFF;
#pragma unroll
    for (int it = 0; it < 15; ++it) {
        const unsigned mid = (lo + hi) >> 1;
        int c = 0;
#pragma unroll
        for (int j = 0; j < 8; ++j) c += ((unsigned)v0[j] <= mid) + ((unsigned)v1[j] <= mid);
        c = wred_sum_i(c);
        if (c >= TOPK) hi = mid; else lo = mid + 1;
    }
    if (lane == 0) {
        u16 b = (u16)lo;
        _Float16 h;
        __builtin_memcpy(&h, &b, 2);
        tauB[row] = (float)h + 2.0f;
    }
}

// ---------------- kernel 5: per-row top-21 stats + LID ----
__global__ __launch_bounds__(256) void finalize_kernel(const float* __restrict__ cand_g,
                                                       const int* __restrict__ cnt_g,
                                                       float* __restrict__ out) {
    const int tid  = threadIdx.x;
    const int lane = tid & 63;
    const int row  = blockIdx.x * 4 + (tid >> 6);

    int cnt = cnt_g[row];
    if (cnt > CAPG) cnt = CAPG;
    const float INFV = __uint_as_float(0x7F800000u);

    float v[5];
    unsigned b[5];
#pragma unroll
    for (int j = 0; j < 5; ++j) {
        const int s = lane + 64 * j;
        v[j] = (s < cnt) ? fmaxf(cand_g[(size_t)row * CAPG + s], 0.0f) : INFV;
        b[j] = __float_as_uint(v[j]);
    }

    unsigned lo = 0, hi = 0x7F7FFFFFu;
#pragma unroll
    for (int it = 0; it < 31; ++it) {
        const unsigned mid = (lo + hi) >> 1;
        int c = 0;
#pragma unroll
        for (int j = 0; j < 5; ++j) c += (b[j] <= mid);
        c = wred_sum_i(c);
        if (c >= TOPK) hi = mid; else lo = mid + 1;
    }
    const float th = __uint_as_float(lo);

    int clt = 0;
    float slt = 0.f, mn = INFV;
#pragma unroll
    for (int j = 0; j < 5; ++j) {
        if (b[j] < lo) {
            clt += 1;
            slt += sqrtf(fmaxf(v[j], 1e-12f));
        }
        mn = fminf(mn, v[j]);
    }
    clt = wred_sum_i(clt);
    slt = wred_sum_f(slt);
    mn  = wred_min_f(mn);

    if (lane == 0) {
        const float a20 = sqrtf(fmaxf(th, 1e-12f));
        const float a0  = sqrtf(fmaxf(mn, 1e-12f));
        const float S21 = slt + (float)(TOPK - clt) * a20;
        const float m   = (S21 - a0 - a20) * (1.0f / 19.0f);
        const float lid = m / (a20 - m);
        out[row] = -fabsf(logf(lid));
    }
}

extern "C" void kernel_launch(void* const* d_in, const int* in_sizes, int n_in,
                              void* d_out, int out_size, void* d_ws, size_t ws_size,
                              hipStream_t stream) {
    const float* X = (const float*)d_in[0];
    float* out = (float*)d_out;
    char* ws = (char*)d_ws;

    u16*   Xh    = (u16*)ws;                      // 12,582,912 B
    float* norms = (float*)(ws + 12582912);       //     32,768 B
    float* tauB  = (float*)(ws + 12615680);       //     32,768 B
    int*   cnt_g = (int*)(ws + 12648448);         //     32,768 B
    u16*   d2h   = (u16*)(ws + 12681216);         // 16,777,216 B (8192x1024 fp16)
    float* cand_g = (float*)(ws + 12681216);      // aliases d2h (tau_select done first)

    prep_kernel<<<N_PTS, 256, 0, stream>>>(X, Xh, norms, cnt_g);
    gemm_main<0><<<128, 512, 0, stream>>>(Xh, norms, nullptr, d2h, nullptr, nullptr);
    tau_select_kernel<<<N_PTS / 4, 256, 0, stream>>>(d2h, tauB);
    gemm_main<1><<<1024, 512, 0, stream>>>(Xh, norms, tauB, nullptr, cand_g, cnt_g);
    finalize_kernel<<<N_PTS / 4, 256, 0, stream>>>(cand_g, cnt_g, out);
}

// Round 6
// 159.979 us; speedup vs baseline: 1.3807x; 1.3807x over previous
//
#include <hip/hip_runtime.h>
#include <hip/hip_fp16.h>

typedef unsigned short u16;
using f32x4 = __attribute__((ext_vector_type(4))) float;
using half8 = __attribute__((ext_vector_type(8))) _Float16;
using us8   = __attribute__((ext_vector_type(8))) unsigned short;

#define N_PTS 8192
#define D_DIM 768
#define TOPK  21
#define KSTEPS 12
#define CAPL  8          // LDS candidate slots per row per tile-side (E~2.6)
#define CAPG  320        // global candidate slots per row (E~168)

// ---------------- async global->LDS (16B per lane) ----------------
__device__ __forceinline__ void gload16(const void* g, void* l) {
    __builtin_amdgcn_global_load_lds(
        (const __attribute__((address_space(1))) void*)g,
        (__attribute__((address_space(3))) void*)l,
        16, 0, 0);
}

// ---------------- wave (64-lane) reductions ----------------
__device__ __forceinline__ int wred_sum_i(int c) {
#pragma unroll
    for (int o = 32; o >= 1; o >>= 1) c += __shfl_xor(c, o, 64);
    return c;
}
__device__ __forceinline__ float wred_sum_f(float c) {
#pragma unroll
    for (int o = 32; o >= 1; o >>= 1) c += __shfl_xor(c, o, 64);
    return c;
}
__device__ __forceinline__ float wred_min_f(float c) {
#pragma unroll
    for (int o = 32; o >= 1; o >>= 1) c = fminf(c, __shfl_xor(c, o, 64));
    return c;
}

// ---------------- kernel 1: fp32 -> fp16 + row norms + zero counters ----
__global__ __launch_bounds__(256) void prep_kernel(const float* __restrict__ X,
                                                   u16* __restrict__ Xh,
                                                   float* __restrict__ norms,
                                                   int* __restrict__ cnt_g) {
    const int row = blockIdx.x;
    const int tid = threadIdx.x;
    const float* xr = X + (size_t)row * D_DIM;
    u16* hr = Xh + (size_t)row * D_DIM;
    float s = 0.f;
#pragma unroll
    for (int i = 0; i < 3; ++i) {
        float v = xr[tid + i * 256];
        _Float16 h = (_Float16)v;
        u16 hb;
        __builtin_memcpy(&hb, &h, 2);
        hr[tid + i * 256] = hb;
        float vb = (float)h;
        s += vb * vb;
    }
#pragma unroll
    for (int o = 32; o >= 1; o >>= 1) s += __shfl_down(s, o, 64);
    __shared__ float red[4];
    if ((tid & 63) == 0) red[tid >> 6] = s;
    __syncthreads();
    if (tid == 0) {
        norms[row] = red[0] + red[1] + red[2] + red[3];
        cnt_g[row] = 0;
    }
}

// ---------------- kernel 2: sample GEMM (cols 0..1023) -> d2 as fp16 ----
// R3-proven 128x128 single-buffer structure; 512 blocks.
__global__ __launch_bounds__(256, 4) void gemm_tau_kernel(const u16* __restrict__ Xh,
                                                          const float* __restrict__ norms,
                                                          u16* __restrict__ d2h) {
    __shared__ __align__(16) u16 As[128 * 64];
    __shared__ __align__(16) u16 Bs[128 * 64];
    __shared__ float nAs[128];
    __shared__ float nBs[128];

    const int tid  = threadIdx.x;
    const int lane = tid & 63;
    const int wid  = tid >> 6;
    const int wr   = wid >> 1;
    const int wc   = wid & 1;
    const int l16  = lane >> 4;
    const int l15  = lane & 15;

    const int bid = blockIdx.x;
    const int swz = (bid & 7) * 64 + (bid >> 3);
    const int rowTile = swz >> 3;
    const int chunk   = swz & 7;
    const int r0 = rowTile * 128;
    const int cb = chunk * 128;

    if (tid < 128) {
        nAs[tid] = norms[r0 + tid];
        nBs[tid] = norms[cb + tid];
    }

    const int rb   = tid >> 3;
    const int cole = (tid & 7) * 8;
    const int lofs = tid * 8;

    f32x4 acc[4][4];
#pragma unroll
    for (int m = 0; m < 4; ++m)
#pragma unroll
        for (int n = 0; n < 4; ++n) {
            f32x4 z = {0.f, 0.f, 0.f, 0.f};
            acc[m][n] = z;
        }

    for (int ks = 0; ks < KSTEPS; ++ks) {
        const int kofs = ks * 64;
#pragma unroll
        for (int i = 0; i < 4; ++i) {
            const int r = i * 32 + rb;
            gload16(Xh + (size_t)(r0 + r) * D_DIM + kofs + cole, &As[i * 2048 + lofs]);
            gload16(Xh + (size_t)(cb + r) * D_DIM + kofs + cole, &Bs[i * 2048 + lofs]);
        }
        __syncthreads();
#pragma unroll
        for (int kk = 0; kk < 2; ++kk) {
            const int ko = kk * 32 + l16 * 8;
            half8 af[4], bf[4];
#pragma unroll
            for (int m = 0; m < 4; ++m)
                af[m] = *reinterpret_cast<const half8*>(&As[(wr * 64 + m * 16 + l15) * 64 + ko]);
#pragma unroll
            for (int n = 0; n < 4; ++n)
                bf[n] = *reinterpret_cast<const half8*>(&Bs[(wc * 64 + n * 16 + l15) * 64 + ko]);
#pragma unroll
            for (int m = 0; m < 4; ++m)
#pragma unroll
                for (int n = 0; n < 4; ++n)
                    acc[m][n] = __builtin_amdgcn_mfma_f32_16x16x32_f16(af[m], bf[n], acc[m][n], 0, 0, 0);
        }
        __syncthreads();
    }

    float nAr[4][4], nBc[4];
#pragma unroll
    for (int m = 0; m < 4; ++m)
#pragma unroll
        for (int r = 0; r < 4; ++r) nAr[m][r] = nAs[wr * 64 + m * 16 + l16 * 4 + r];
#pragma unroll
    for (int n = 0; n < 4; ++n) nBc[n] = nBs[wc * 64 + n * 16 + l15];

#pragma unroll
    for (int m = 0; m < 4; ++m)
#pragma unroll
        for (int n = 0; n < 4; ++n)
#pragma unroll
            for (int r = 0; r < 4; ++r) {
                const int ri = r0 + wr * 64 + m * 16 + l16 * 4 + r;
                const int ci = cb + wc * 64 + n * 16 + l15;
                float d2 = fmaxf(nAr[m][r] + nBc[n] - 2.0f * acc[m][n][r], 0.0f);
                _Float16 h = (_Float16)d2;
                u16 hb;
                __builtin_memcpy(&hb, &h, 2);
                d2h[(size_t)ri * 1024 + ci] = hb;
            }
}

// ---------------- kernel 3: per-row 21st-smallest of sample (bit search) ----
__global__ __launch_bounds__(256) void tau_select_kernel(const u16* __restrict__ d2h,
                                                         float* __restrict__ tauB) {
    const int tid  = threadIdx.x;
    const int lane = tid & 63;
    const int row  = blockIdx.x * 4 + (tid >> 6);

    const us8* p = (const us8*)(d2h + (size_t)row * 1024);
    us8 v0 = p[lane * 2];
    us8 v1 = p[lane * 2 + 1];

    unsigned lo = 0, hi = 0x7BFF;
#pragma unroll
    for (int it = 0; it < 15; ++it) {
        const unsigned mid = (lo + hi) >> 1;
        int c = 0;
#pragma unroll
        for (int j = 0; j < 8; ++j) c += ((unsigned)v0[j] <= mid) + ((unsigned)v1[j] <= mid);
        c = wred_sum_i(c);
        if (c >= TOPK) hi = mid; else lo = mid + 1;
    }
    if (lane == 0) {
        u16 b = (u16)lo;
        _Float16 h;
        __builtin_memcpy(&h, &b, 2);
        tauB[row] = (float)h + 2.0f;   // upper bound on true 21st d2, + fp16 slack
    }
}

// ---------------- kernel 4: SYMMETRIC upper-triangle GEMM + two-sided filter ----
// 2080 = 64*65/2 tiles of 128x128 (i<=j). Off-diagonal tiles emit candidates
// for rows (row-side) AND columns (col-side, exploiting d(i,j)=d(j,i)).
// Diagonal tiles emit row-side only (symmetric pair covered in-tile).
__global__ __launch_bounds__(256, 3) void gemm_filter_sym(const u16* __restrict__ Xh,
                                                          const float* __restrict__ norms,
                                                          const float* __restrict__ tauB,
                                                          float* __restrict__ cand_g,
                                                          int* __restrict__ cnt_g) {
    __shared__ __align__(16) u16 As[128 * 64];       // 16 KiB
    __shared__ __align__(16) u16 Bs[128 * 64];       // 16 KiB
    __shared__ float candR[128 * CAPL];              // 4 KiB
    __shared__ float candC[128 * CAPL];              // 4 KiB
    __shared__ int   cntR[128];
    __shared__ int   cntC[128];
    __shared__ float nAs[128], nBs[128], tA[128], tB[128];

    const int tid  = threadIdx.x;
    const int lane = tid & 63;
    const int wid  = tid >> 6;
    const int wr   = wid >> 1;
    const int wc   = wid & 1;
    const int l16  = lane >> 4;
    const int l15  = lane & 15;

    // XCD swizzle (2080 = 8 * 260) then triangular decode: b = j*(j+1)/2 + i, i<=j
    const int b = (blockIdx.x & 7) * 260 + (blockIdx.x >> 3);
    int j = (int)((sqrtf(8.0f * (float)b + 1.0f) - 1.0f) * 0.5f);
    while ((j + 1) * (j + 2) / 2 <= b) ++j;
    while (j * (j + 1) / 2 > b) --j;
    const int i = b - j * (j + 1) / 2;
    const int r0 = i * 128;
    const int c0 = j * 128;
    const bool diag = (i == j);

    if (tid < 128) {
        nAs[tid] = norms[r0 + tid];
        tA[tid]  = tauB[r0 + tid];
        nBs[tid] = norms[c0 + tid];
        tB[tid]  = tauB[c0 + tid];
        cntR[tid] = 0;
        cntC[tid] = 0;
    }

    // staging geometry: 8 lanes per 128B row; T2 source-side XOR swizzle
    const int rb  = tid >> 3;                         // row within 32-row group
    const int chS = (tid & 7) ^ ((tid >> 3) & 7);     // pre-swizzled source chunk
    const int lofs = tid * 8;                         // linear LDS dest (elems)

    f32x4 acc[4][4];
#pragma unroll
    for (int m = 0; m < 4; ++m)
#pragma unroll
        for (int n = 0; n < 4; ++n) {
            f32x4 z = {0.f, 0.f, 0.f, 0.f};
            acc[m][n] = z;
        }

    for (int ks = 0; ks < KSTEPS; ++ks) {
        const int kofs = ks * 64 + chS * 8;
#pragma unroll
        for (int it = 0; it < 4; ++it) {
            const int r = it * 32 + rb;
            gload16(Xh + (size_t)(r0 + r) * D_DIM + kofs, &As[it * 2048 + lofs]);
            gload16(Xh + (size_t)(c0 + r) * D_DIM + kofs, &Bs[it * 2048 + lofs]);
        }
        __syncthreads();
#pragma unroll
        for (int kk = 0; kk < 2; ++kk) {
            half8 af[4], bf[4];
#pragma unroll
            for (int m = 0; m < 4; ++m) {
                const int ra = wr * 64 + m * 16 + l15;
                const int ch = (kk * 4 + l16) ^ (ra & 7);
                af[m] = *reinterpret_cast<const half8*>(&As[ra * 64 + ch * 8]);
            }
#pragma unroll
            for (int n = 0; n < 4; ++n) {
                const int rc = wc * 64 + n * 16 + l15;
                const int ch = (kk * 4 + l16) ^ (rc & 7);
                bf[n] = *reinterpret_cast<const half8*>(&Bs[rc * 64 + ch * 8]);
            }
#pragma unroll
            for (int m = 0; m < 4; ++m)
#pragma unroll
                for (int n = 0; n < 4; ++n)
                    acc[m][n] = __builtin_amdgcn_mfma_f32_16x16x32_f16(af[m], bf[n], acc[m][n], 0, 0, 0);
        }
        __syncthreads();
    }

    // ---- two-sided filter epilogue ----
    float nBc[4], tBc[4];
#pragma unroll
    for (int n = 0; n < 4; ++n) {
        const int ci = wc * 64 + n * 16 + l15;
        nBc[n] = nBs[ci];
        tBc[n] = tB[ci];
    }

#pragma unroll
    for (int m = 0; m < 4; ++m)
#pragma unroll
        for (int r = 0; r < 4; ++r) {
            const int ri = wr * 64 + m * 16 + l16 * 4 + r;
            const float na = nAs[ri];
            const float ta = tA[ri];
#pragma unroll
            for (int n = 0; n < 4; ++n) {
                const float val = na + nBc[n] - 2.0f * acc[m][n][r];
                if (val < ta) {                      // row-side candidate
                    const int idx = atomicAdd(&cntR[ri], 1);
                    if (idx < CAPL) candR[ri * CAPL + idx] = val;
                    else {
                        const int g = atomicAdd(&cnt_g[r0 + ri], 1);
                        if (g < CAPG) cand_g[(size_t)(r0 + ri) * CAPG + g] = val;
                    }
                }
                if (!diag && val < tBc[n]) {         // col-side candidate
                    const int ci = wc * 64 + n * 16 + l15;
                    const int idx = atomicAdd(&cntC[ci], 1);
                    if (idx < CAPL) candC[ci * CAPL + idx] = val;
                    else {
                        const int g = atomicAdd(&cnt_g[c0 + ci], 1);
                        if (g < CAPG) cand_g[(size_t)(c0 + ci) * CAPG + g] = val;
                    }
                }
            }
        }

    __syncthreads();
    if (tid < 128) {
        {   // row-side writeout
            const int row = r0 + tid;
            const int c = (cntR[tid] < CAPL) ? cntR[tid] : CAPL;
            if (c > 0) {
                const int base = atomicAdd(&cnt_g[row], c);
                for (int q = 0; q < c; ++q) {
                    const int s = base + q;
                    if (s < CAPG) cand_g[(size_t)row * CAPG + s] = candR[tid * CAPL + q];
                }
            }
        }
        if (!diag) {   // col-side writeout
            const int row = c0 + tid;
            const int c = (cntC[tid] < CAPL) ? cntC[tid] : CAPL;
            if (c > 0) {
                const int base = atomicAdd(&cnt_g[row], c);
                for (int q = 0; q < c; ++q) {
                    const int s = base + q;
                    if (s < CAPG) cand_g[(size_t)row * CAPG + s] = candC[tid * CAPL + q];
                }
            }
        }
    }
}

// ---------------- kernel 5: per-row top-21 stats + LID ----
__global__ __launch_bounds__(256) void finalize_kernel(const float* __restrict__ cand_g,
                                                       const int* __restrict__ cnt_g,
                                                       float* __restrict__ out) {
    const int tid  = threadIdx.x;
    const int lane = tid & 63;
    const int row  = blockIdx.x * 4 + (tid >> 6);

    int cnt = cnt_g[row];
    if (cnt > CAPG) cnt = CAPG;
    const float INFV = __uint_as_float(0x7F800000u);

    float v[5];
    unsigned b[5];
#pragma unroll
    for (int j = 0; j < 5; ++j) {
        const int s = lane + 64 * j;
        v[j] = (s < cnt) ? fmaxf(cand_g[(size_t)row * CAPG + s], 0.0f) : INFV;
        b[j] = __float_as_uint(v[j]);
    }

    unsigned lo = 0, hi = 0x7F7FFFFFu;
#pragma unroll
    for (int it = 0; it < 31; ++it) {
        const unsigned mid = (lo + hi) >> 1;
        int c = 0;
#pragma unroll
        for (int j = 0; j < 5; ++j) c += (b[j] <= mid);
        c = wred_sum_i(c);
        if (c >= TOPK) hi = mid; else lo = mid + 1;
    }
    const float th = __uint_as_float(lo);

    int clt = 0;
    float slt = 0.f, mn = INFV;
#pragma unroll
    for (int j = 0; j < 5; ++j) {
        if (b[j] < lo) {
            clt += 1;
            slt += sqrtf(fmaxf(v[j], 1e-12f));
        }
        mn = fminf(mn, v[j]);
    }
    clt = wred_sum_i(clt);
    slt = wred_sum_f(slt);
    mn  = wred_min_f(mn);

    if (lane == 0) {
        const float a20 = sqrtf(fmaxf(th, 1e-12f));
        const float a0  = sqrtf(fmaxf(mn, 1e-12f));
        const float S21 = slt + (float)(TOPK - clt) * a20;
        const float m   = (S21 - a0 - a20) * (1.0f / 19.0f);
        const float lid = m / (a20 - m);
        out[row] = -fabsf(logf(lid));
    }
}

extern "C" void kernel_launch(void* const* d_in, const int* in_sizes, int n_in,
                              void* d_out, int out_size, void* d_ws, size_t ws_size,
                              hipStream_t stream) {
    const float* X = (const float*)d_in[0];
    float* out = (float*)d_out;
    char* ws = (char*)d_ws;

    u16*   Xh    = (u16*)ws;                      // 12,582,912 B
    float* norms = (float*)(ws + 12582912);       //     32,768 B
    float* tauB  = (float*)(ws + 12615680);       //     32,768 B
    int*   cnt_g = (int*)(ws + 12648448);         //     32,768 B
    u16*   d2h   = (u16*)(ws + 12681216);         // 16,777,216 B (8192x1024 fp16)
    float* cand_g = (float*)(ws + 12681216);      // aliases d2h (tau_select done first)

    prep_kernel<<<N_PTS, 256, 0, stream>>>(X, Xh, norms, cnt_g);
    gemm_tau_kernel<<<512, 256, 0, stream>>>(Xh, norms, d2h);
    tau_select_kernel<<<N_PTS / 4, 256, 0, stream>>>(d2h, tauB);
    gemm_filter_sym<<<2080, 256, 0, stream>>>(Xh, norms, tauB, cand_g, cnt_g);
    finalize_kernel<<<N_PTS / 4, 256, 0, stream>>>(cand_g, cnt_g, out);
}